// Round 1
// baseline (73.712 us; speedup 1.0000x reference)
//
#include <hip/hip_runtime.h>
#include <math.h>

// Problem constants (from reference)
constexpr int NODE_NUM = 1000000;
constexpr int TYPE_NUM = 4;
constexpr int DIM      = 128;
constexpr int K        = 5;
constexpr int M        = 5;
constexpr int B        = 256;
constexpr int LK       = 75;          // L - K
constexpr int NBL      = B * LK;      // 19200 (b,l) pairs
constexpr int PS       = NBL * K;     // 96000  pos_score elems
constexpr int NS       = NBL * K * M; // 480000 neg_score elems

// Output layout (concatenated flat, all float32):
// [0,          PS)                : pos_score
// [PS,         PS+NS)             : neg_score
// [PS+NS,      PS+NS+PS)          : pos_pair_type_out (as float)
// [PS+NS+PS,   PS+NS+PS+NS)      : neg_pair_type_out (as float)

__device__ __forceinline__ float wave_reduce_sum(float v) {
    #pragma unroll
    for (int m = 32; m >= 1; m >>= 1)
        v += __shfl_xor(v, m, 64);
    return v;
}

__global__ __launch_bounds__(256) void skipgram_kernel(
    const int*   __restrict__ walk,       // [NBL]
    const int*   __restrict__ pos,        // [NBL*K]
    const int*   __restrict__ neg,        // [NBL*K*M]
    const int*   __restrict__ walk_type,  // [NBL]
    const int*   __restrict__ pos_type,   // [NBL*K]
    const int*   __restrict__ neg_type,   // [NBL*K*M]
    const float* __restrict__ node_emb,   // [NODE_NUM*DIM]
    const float* __restrict__ rel_emb,    // [16*DIM]
    float*       __restrict__ out)
{
    // Stage sigmoid(relationship_embedding) in LDS: 16*128 floats = 8 KB
    __shared__ float sig[TYPE_NUM * TYPE_NUM * DIM];
    const int tid = threadIdx.x;
    for (int i = tid; i < TYPE_NUM * TYPE_NUM * DIM; i += 256) {
        float x = rel_emb[i];
        sig[i] = 1.0f / (1.0f + expf(-x));
    }
    __syncthreads();

    const int wave = tid >> 6;
    const int lane = tid & 63;
    const int idx  = blockIdx.x * 4 + wave;   // b*LK + l
    if (idx >= NBL) return;

    const int wnode = walk[idx];
    const int wt    = walk_type[idx];

    // walk embedding fragment: lane holds dims [2*lane, 2*lane+1]
    const float2 we = *(const float2*)(node_emb + (size_t)wnode * DIM + 2 * lane);

    // ---------------- positive samples ----------------
    float ppart[K];
    int   ppt[K];
    #pragma unroll
    for (int k = 0; k < K; ++k) {
        const int p   = pos[idx * K + k];
        const int ptp = pos_type[idx * K + k];
        ppt[k] = TYPE_NUM * wt + ptp;
        const float2 pe = *(const float2*)(node_emb + (size_t)p * DIM + 2 * lane);
        const float2 sg = *(const float2*)(sig + ppt[k] * DIM + 2 * lane);
        ppart[k] = we.x * pe.x * sg.x + we.y * pe.y * sg.y;
    }
    #pragma unroll
    for (int k = 0; k < K; ++k) {
        const float s = wave_reduce_sum(ppart[k]);
        if (lane == 0) {
            out[idx * K + k]           = s;
            out[PS + NS + idx * K + k] = (float)(TYPE_NUM * TYPE_NUM * k + ppt[k]);
        }
    }

    // ---------------- negative samples ----------------
    #pragma unroll
    for (int k = 0; k < K; ++k) {
        float npart[M];
        int   npt[M];
        #pragma unroll
        for (int m = 0; m < M; ++m) {
            const int nidx = (idx * K + k) * M + m;
            const int n    = neg[nidx];
            const int ntp  = neg_type[nidx];
            npt[m] = TYPE_NUM * wt + ntp;
            const float2 ne = *(const float2*)(node_emb + (size_t)n * DIM + 2 * lane);
            const float2 sg = *(const float2*)(sig + npt[m] * DIM + 2 * lane);
            npart[m] = we.x * ne.x * sg.x + we.y * ne.y * sg.y;
        }
        #pragma unroll
        for (int m = 0; m < M; ++m) {
            const float s = wave_reduce_sum(npart[m]);
            const int nidx = (idx * K + k) * M + m;
            if (lane == 0) {
                out[PS + nidx]           = s;
                out[PS + NS + PS + nidx] = (float)(TYPE_NUM * TYPE_NUM * k + npt[m]);
            }
        }
    }
}

extern "C" void kernel_launch(void* const* d_in, const int* in_sizes, int n_in,
                              void* d_out, int out_size, void* d_ws, size_t ws_size,
                              hipStream_t stream) {
    const int*   walk      = (const int*)d_in[0];
    const int*   pos       = (const int*)d_in[1];
    const int*   neg       = (const int*)d_in[2];
    const int*   walk_type = (const int*)d_in[3];
    const int*   pos_type  = (const int*)d_in[4];
    const int*   neg_type  = (const int*)d_in[5];
    const float* node_emb  = (const float*)d_in[6];
    const float* rel_emb   = (const float*)d_in[7];
    float* out = (float*)d_out;

    const int blocks = NBL / 4;  // 4 waves per block, one (b,l) per wave
    skipgram_kernel<<<blocks, 256, 0, stream>>>(
        walk, pos, neg, walk_type, pos_type, neg_type, node_emb, rel_emb, out);
}

// Round 2
// 54.360 us; speedup vs baseline: 1.3560x; 1.3560x over previous
//
#include <hip/hip_runtime.h>
#include <math.h>

// Problem constants (from reference)
constexpr int NODE_NUM = 1000000;
constexpr int TYPE_NUM = 4;
constexpr int DIM      = 128;
constexpr int K        = 5;
constexpr int M        = 5;
constexpr int B        = 256;
constexpr int LK       = 75;          // L - K
constexpr int NBL      = B * LK;      // 19200 (b,l) pairs
constexpr int PS       = NBL * K;     // 96000  pos_score elems
constexpr int NS       = NBL * K * M; // 480000 neg_score elems

// Output layout (concatenated flat, all float32):
// [0,        PS)            : pos_score
// [PS,       PS+NS)         : neg_score
// [PS+NS,    PS+NS+PS)      : pos_pair_type_out (as float)
// [PS+NS+PS, PS+NS+PS+NS)   : neg_pair_type_out (as float)

__global__ __launch_bounds__(256) void skipgram_kernel(
    const int*   __restrict__ walk,       // [NBL]
    const int*   __restrict__ pos,        // [NBL*K]
    const int*   __restrict__ neg,        // [NBL*K*M]
    const int*   __restrict__ walk_type,  // [NBL]
    const int*   __restrict__ pos_type,   // [NBL*K]
    const int*   __restrict__ neg_type,   // [NBL*K*M]
    const float* __restrict__ node_emb,   // [NODE_NUM*DIM]
    const float* __restrict__ rel_emb,    // [16*DIM]
    float*       __restrict__ out)
{
    // Stage sigmoid(relationship_embedding) in LDS: 16*128 floats = 8 KB
    __shared__ float sig[TYPE_NUM * TYPE_NUM * DIM];
    const int tid = threadIdx.x;
    for (int i = tid; i < TYPE_NUM * TYPE_NUM * DIM; i += 256) {
        const float x = rel_emb[i];
        sig[i] = 1.0f / (1.0f + expf(-x));
    }
    __syncthreads();

    const int wave = tid >> 6;
    const int lane = tid & 63;
    const int half = lane >> 5;   // 0: even row of pair, 1: odd row
    const int hl   = lane & 31;   // position within 32-lane half (dims 4*hl..4*hl+3)

    int idx = blockIdx.x * 4 + wave;                 // b*LK + l  (wave-uniform)
    idx = __builtin_amdgcn_readfirstlane(idx);       // force scalar → s_load for indices

    const int wnode = walk[idx];
    const int wt    = walk_type[idx];

    // walk embedding fragment: both halves load the same 16B (HW coalesces)
    const float4 we = *(const float4*)(node_emb + (size_t)wnode * DIM + 4 * hl);

    // Row r in [0,30): r<5 -> pos sample r; else neg sample r-5.
    // Pair j covers rows {2j, 2j+1}: half 0 takes row 2j, half 1 takes row 2j+1.

    // Types for all 30 rows (scalar loads, kept for gate lookup + type output)
    int tpA[15], tpB[15];
    #pragma unroll
    for (int j = 0; j < 15; ++j) {
        const int r0 = 2 * j, r1 = 2 * j + 1;
        tpA[j] = (r0 < K) ? pos_type[idx * K + r0] : neg_type[idx * K * M + r0 - K];
        tpB[j] = (r1 < K) ? pos_type[idx * K + r1] : neg_type[idx * K * M + r1 - K];
    }

    // Issue all 15 paired gathers up-front (1 KB per instruction per wave)
    float4 ev[15];
    #pragma unroll
    for (int j = 0; j < 15; ++j) {
        const int r0 = 2 * j, r1 = 2 * j + 1;
        const int i0 = (r0 < K) ? pos[idx * K + r0] : neg[idx * K * M + r0 - K];
        const int i1 = (r1 < K) ? pos[idx * K + r1] : neg[idx * K * M + r1 - K];
        const int myid = half ? i1 : i0;
        ev[j] = *(const float4*)(node_emb + (size_t)myid * DIM + 4 * hl);
    }

    // Partial dot per row: walk_e * sigmoid(rel) * sample_e over this lane's 4 dims
    float p[15];
    #pragma unroll
    for (int j = 0; j < 15; ++j) {
        const int mypt = half ? tpB[j] : tpA[j];
        const float4 sg = *(const float4*)(&sig[(TYPE_NUM * wt + mypt) * DIM + 4 * hl]);
        p[j] = we.x * sg.x * ev[j].x + we.y * sg.y * ev[j].y
             + we.z * sg.z * ev[j].z + we.w * sg.w * ev[j].w;
    }

    // Butterfly reduce within each 32-lane half (both rows of a pair at once)
    #pragma unroll
    for (int j = 0; j < 15; ++j) {
        float v = p[j];
        #pragma unroll
        for (int m2 = 16; m2 >= 1; m2 >>= 1) v += __shfl_xor(v, m2, 64);
        p[j] = v;
    }

    // Stores: lane hl==0 of each half writes its row's score + pair-type code
    #pragma unroll
    for (int j = 0; j < 15; ++j) {
        const int r    = 2 * j + half;
        const int mytp = half ? tpB[j] : tpA[j];
        if (hl == 0) {
            if (r < K) {
                out[idx * K + r]           = p[j];
                out[PS + NS + idx * K + r] = (float)(TYPE_NUM * TYPE_NUM * r + TYPE_NUM * wt + mytp);
            } else {
                const int rr = r - K;            // 0..24
                const int k  = rr / M;           // window offset (compile-time per j,half)
                out[PS + idx * K * M + rr]           = p[j];
                out[PS + NS + PS + idx * K * M + rr] = (float)(TYPE_NUM * TYPE_NUM * k + TYPE_NUM * wt + mytp);
            }
        }
    }
}

extern "C" void kernel_launch(void* const* d_in, const int* in_sizes, int n_in,
                              void* d_out, int out_size, void* d_ws, size_t ws_size,
                              hipStream_t stream) {
    const int*   walk      = (const int*)d_in[0];
    const int*   pos       = (const int*)d_in[1];
    const int*   neg       = (const int*)d_in[2];
    const int*   walk_type = (const int*)d_in[3];
    const int*   pos_type  = (const int*)d_in[4];
    const int*   neg_type  = (const int*)d_in[5];
    const float* node_emb  = (const float*)d_in[6];
    const float* rel_emb   = (const float*)d_in[7];
    float* out = (float*)d_out;

    const int blocks = NBL / 4;  // 4 waves per block, one (b,l) per wave
    skipgram_kernel<<<blocks, 256, 0, stream>>>(
        walk, pos, neg, walk_type, pos_type, neg_type, node_emb, rel_emb, out);
}